// Round 9
// baseline (138.302 us; speedup 1.0000x reference)
//
#include <hip/hip_runtime.h>

#define NB   32
#define NC   3
#define NH   512
#define NW   512
#define KS   25
#define HALF 12
#define NS   60
#define PLN  (NH * NW)        // 262144
#define NPL  (NB * NC)        // 96

// ---- workspace layout ----
#define HB_BYTES  ((size_t)NPL * PLN * 4)             // 100,663,296
#define WTS_OFF   HB_BYTES
#define WTS_BYTES ((size_t)4096)                      // 32 x 28 floats, padded
#define NL_OFF    (WTS_OFF + WTS_BYTES)
#define NL_BYTES  ((size_t)NB * NW * 4)
#define PK_OFF    (NL_OFF + NL_BYTES)
#define PK_BYTES  ((size_t)NB * NW * NS * 4)
#define WS_NEED   (PK_OFF + PK_BYTES)                 // ~104.7 MB

__device__ __forceinline__ float clip01(float v) { return fminf(fmaxf(v, 0.f), 1.f); }

struct PParams {
  int f1, f2, f3, f4;
  float intensity, cx, cy, rxi, ryi;
  float oy0, oy1, ox0, ox1;
  float log1ma;
  float thr_lo, thr_hi;
};

__device__ __forceinline__ PParams load_params(
    int b, const int* __restrict__ flags, const float* __restrict__ glare_u,
    const float* __restrict__ occ_u, const float* __restrict__ rain_alpha_u,
    const float* __restrict__ noise_amt_u)
{
  PParams P;
  P.f1 = flags[b * 5 + 1] > 0;
  P.f2 = flags[b * 5 + 2] > 0;
  P.f3 = flags[b * 5 + 3] > 0;
  P.f4 = flags[b * 5 + 4] > 0;
  float g0 = glare_u[b * 5 + 0], g1 = glare_u[b * 5 + 1], g2 = glare_u[b * 5 + 2],
        g3 = glare_u[b * 5 + 3], g4 = glare_u[b * 5 + 4];
  P.intensity = 0.4f + 0.5f * g0;
  P.rxi = 1.f / ((0.1f + 0.25f * g1) * 256.f);
  P.ryi = 1.f / ((0.1f + 0.25f * g2) * 256.f);
  P.cx = (0.2f + 0.6f * g3) * 512.f;
  P.cy = (0.2f + 0.6f * g4) * 512.f;
  float o0 = occ_u[b * 4 + 0], o1 = occ_u[b * 4 + 1],
        o2 = occ_u[b * 4 + 2], o3 = occ_u[b * 4 + 3];
  float ph = floorf(512.f * (0.1f + 0.3f * o0));
  float pw = floorf(512.f * (0.1f + 0.3f * o1));
  P.oy0 = floorf(o2 * (512.f - ph)); P.oy1 = P.oy0 + ph;
  P.ox0 = floorf(o3 * (512.f - pw)); P.ox1 = P.ox0 + pw;
  P.log1ma = log2f(1.f - (0.15f + 0.35f * rain_alpha_u[b]));
  float half_amt = 0.5f * (0.01f + 0.07f * noise_amt_u[b]);
  P.thr_lo = half_amt; P.thr_hi = 1.f - half_amt;
  return P;
}

// ---- prep: rain column lists (blocks 0..63) + per-sample blur weights (block 64) ----
__global__ void prep_kernel(const float* __restrict__ rain_u,
                            const float* __restrict__ rain_n_u,
                            const float* __restrict__ sigma_u,
                            int* __restrict__ nlist,
                            unsigned* __restrict__ packed,
                            float* __restrict__ wts)
{
  if (blockIdx.x == 64) {
    int b = threadIdx.x;
    if (b < NB) {
      float sig = 1.f + 3.f * sigma_u[b];
      float ninv = -1.f / (2.f * sig * sig);
      float w[KS]; float s = 0.f;
      #pragma unroll
      for (int j = 0; j < KS; ++j) {
        float d = (float)j - 12.f;
        w[j] = __expf(d * d * ninv);
        s += w[j];
      }
      float inv = 1.f / s;
      #pragma unroll
      for (int j = 0; j < KS; ++j) wts[b * 28 + j] = w[j] * inv;
    }
    return;
  }
  int t = blockIdx.x * 256 + threadIdx.x;      // [0, 32*512)
  if (t >= NB * NW) return;
  int b = t >> 9, wcol = t & 511;
  float n = floorf(20.f + 41.f * rain_n_u[b]);
  float wf = (float)wcol;
  int cnt = 0;
  for (int s = 0; s < NS; ++s) {
    if ((float)s < n) {
      float xc = floorf(rain_u[(b * NS + s) * 3 + 0] * 512.f);
      if (wf >= xc - 1.f && wf <= xc) {
        float y0 = floorf(rain_u[(b * NS + s) * 3 + 1] * 256.f);
        float y1 = 256.f + floorf(rain_u[(b * NS + s) * 3 + 2] * 256.f);
        packed[t * NS + cnt] = (((unsigned)y0) << 16) | (unsigned)y1;
        ++cnt;
      }
    }
  }
  nlist[t] = cnt;
}

// ---- K1: H-blur row streamer. Interior/edge split is thread-REMAPPED so
// waves 0-2 are 100% branch-free float4 (r8's q-test was lane-divergent in
// EVERY wave -> each wave issued 7 vector + 28 scalar loads = 5x). ----
__global__ __launch_bounds__(256, 4)
void hblur_kernel(const float* __restrict__ x, const int* __restrict__ flags,
                  const float* __restrict__ wts, float* __restrict__ hb)
{
  const int b = blockIdx.z;
  if (flags[b * 5] <= 0) return;               // non-blur sample: nothing to do
  const int ch = blockIdx.y;
  const int tid = threadIdx.x;
  const int r0 = blockIdx.x << 1;              // 2 rows per block

  float w[KS];
  const float* wp = wts + b * 28;              // sample-uniform -> scalar loads
  #pragma unroll
  for (int j = 0; j < KS; ++j) w[j] = wp[j];

  const size_t plane = (size_t)(b * NC + ch) * PLN;

  if (tid < 244) {
    // interior quads 3..124 of the two rows; waves 0-2 fully uniform
    int row = r0 + (tid >= 122);
    int q = (tid >= 122 ? tid - 122 : tid) + 3;
    int gx0 = q << 2;
    const float* rowp = x + plane + (size_t)row * NW;
    float win[28];
    #pragma unroll
    for (int j = 0; j < 7; ++j) {
      float4 v = *reinterpret_cast<const float4*>(rowp + gx0 - HALF + 4 * j);
      win[4 * j + 0] = v.x; win[4 * j + 1] = v.y;
      win[4 * j + 2] = v.z; win[4 * j + 3] = v.w;
    }
    float a0 = 0.f, a1 = 0.f, a2 = 0.f, a3 = 0.f;
    #pragma unroll
    for (int t = 0; t < KS; ++t) {
      float wt = w[t];
      a0 = fmaf(wt, win[t + 0], a0);
      a1 = fmaf(wt, win[t + 1], a1);
      a2 = fmaf(wt, win[t + 2], a2);
      a3 = fmaf(wt, win[t + 3], a3);
    }
    *reinterpret_cast<float4*>(hb + plane + (size_t)row * NW + gx0) =
        make_float4(a0, a1, a2, a3);
  } else {
    // 12 edge quads (6 per row) handled by wave 3 only
    int e = tid - 244;                         // 0..11
    int row = r0 + (e >= 6);
    int es = (e >= 6 ? e - 6 : e);             // 0..5
    int q = (es < 3) ? es : (122 + es);        // {0,1,2,125,126,127}
    int gx0 = q << 2;
    const float* rowp = x + plane + (size_t)row * NW;
    float win[28];
    #pragma unroll
    for (int j = 0; j < 28; ++j) {
      int gx = gx0 - HALF + j;
      win[j] = ((unsigned)gx < (unsigned)NW) ? rowp[gx] : 0.f;
    }
    float a0 = 0.f, a1 = 0.f, a2 = 0.f, a3 = 0.f;
    #pragma unroll
    for (int t = 0; t < KS; ++t) {
      float wt = w[t];
      a0 = fmaf(wt, win[t + 0], a0);
      a1 = fmaf(wt, win[t + 1], a1);
      a2 = fmaf(wt, win[t + 2], a2);
      a3 = fmaf(wt, win[t + 3], a3);
    }
    *reinterpret_cast<float4*>(hb + plane + (size_t)row * NW + gx0) =
        make_float4(a0, a1, a2, a3);
  }
}

// ---- chain on a 4-col x 8-row quad block (all static indexing) ----
__device__ __forceinline__ void chain_quad(
    float a[8][4], const PParams& P, int b, int gx0, int gy0,
    const float* __restrict__ np_plane, const int* __restrict__ nlist,
    const unsigned* __restrict__ packed, float* __restrict__ op_plane)
{
  if (P.f1) {
    float dx2[4];
    #pragma unroll
    for (int c = 0; c < 4; ++c) {
      float dx = ((float)(gx0 + c) - P.cx) * P.rxi;
      dx2[c] = dx * dx;
    }
    #pragma unroll
    for (int k = 0; k < 8; ++k) {
      float dy = ((float)(gy0 + k) - P.cy) * P.ryi;
      float dy2 = dy * dy;
      #pragma unroll
      for (int c = 0; c < 4; ++c) {
        float g = __expf(-(dx2[c] + dy2));
        a[k][c] = clip01(a[k][c] + P.intensity * g);
      }
    }
  }
  if (P.f2) {
    #pragma unroll
    for (int c = 0; c < 4; ++c) {
      float fx = (float)(gx0 + c);
      if (fx >= P.ox0 && fx < P.ox1) {
        #pragma unroll
        for (int k = 0; k < 8; ++k) {
          float fy = (float)(gy0 + k);
          if (fy >= P.oy0 && fy < P.oy1) a[k][c] = 0.f;
        }
      }
    }
  }
  if (P.f3) {
    #pragma unroll
    for (int c = 0; c < 4; ++c) {
      int base = b * NW + gx0 + c;
      int n = nlist[base];
      if (n > 0) {
        float cnt[8];
        #pragma unroll
        for (int k = 0; k < 8; ++k) cnt[k] = 0.f;
        for (int j = 0; j < n; ++j) {
          unsigned p = packed[base * NS + j];
          float y0 = (float)(p >> 16), y1 = (float)(p & 0xffffu);
          #pragma unroll
          for (int k = 0; k < 8; ++k) {
            float fy = (float)(gy0 + k);
            cnt[k] += (fy >= y0 && fy < y1) ? 1.f : 0.f;
          }
        }
        #pragma unroll
        for (int k = 0; k < 8; ++k) {
          if (cnt[k] != 0.f) {
            float d = exp2f(cnt[k] * P.log1ma);
            a[k][c] = clip01(a[k][c] * d + (1.f - d));
          }
        }
      }
    }
  }
  if (P.f4) {
    #pragma unroll
    for (int k = 0; k < 8; ++k) {
      float4 nv = *reinterpret_cast<const float4*>(
          np_plane + (size_t)(gy0 + k) * NW + gx0);
      a[k][0] = (nv.x < P.thr_lo) ? 0.f : ((nv.x > P.thr_hi) ? 1.f : a[k][0]);
      a[k][1] = (nv.y < P.thr_lo) ? 0.f : ((nv.y > P.thr_hi) ? 1.f : a[k][1]);
      a[k][2] = (nv.z < P.thr_lo) ? 0.f : ((nv.z > P.thr_hi) ? 1.f : a[k][2]);
      a[k][3] = (nv.w < P.thr_lo) ? 0.f : ((nv.w > P.thr_hi) ? 1.f : a[k][3]);
    }
  }
  #pragma unroll
  for (int k = 0; k < 8; ++k)
    *reinterpret_cast<float4*>(op_plane + (size_t)(gy0 + k) * NW + gx0) =
        make_float4(a[k][0], a[k][1], a[k][2], a[k][3]);
}

// ---- K2: V-blur + chain streamer. Interior sub-strips (gy0 in [16,488],
// wave-uniform) take a branch-free fully-unrolled 32-load body so the
// scheduler can keep many loads in flight (r8 had a per-row branch ->
// ~1 outstanding load/wave -> 2 TB/s). ----
__global__ __launch_bounds__(256, 4)
void vchain_kernel(const float* __restrict__ x, const float* __restrict__ hb,
                   const float* __restrict__ wts,
                   const float* __restrict__ glare_u, const float* __restrict__ occ_u,
                   const float* __restrict__ rain_alpha_u,
                   const float* __restrict__ noise_u, const float* __restrict__ noise_amt_u,
                   const int* __restrict__ flags,
                   const int* __restrict__ nlist, const unsigned* __restrict__ packed,
                   float* __restrict__ out)
{
  const int lb = blockIdx.x;
  const int t = (lb & 7) * 384 + (lb >> 3);   // bijective XCD-chunk swizzle
  const int strip = t & 31;                   // 16-row strip within plane
  const int pl = t >> 5;                      // plane 0..95
  const int b = pl / 3;
  const int tid = threadIdx.x;
  const int gy0 = strip * 16 + ((tid >> 7) << 3);   // wave-uniform
  const int gx0 = (tid & 127) << 2;

  const int f0 = flags[b * 5] > 0;
  PParams P = load_params(b, flags, glare_u, occ_u, rain_alpha_u, noise_amt_u);
  const size_t plane = (size_t)pl * PLN;

  float a[8][4];
  if (f0) {
    float w[KS];
    const float* wp = wts + b * 28;
    #pragma unroll
    for (int j = 0; j < KS; ++j) w[j] = wp[j];
    #pragma unroll
    for (int k = 0; k < 8; ++k) {
      a[k][0] = 0.f; a[k][1] = 0.f; a[k][2] = 0.f; a[k][3] = 0.f;
    }
    if (gy0 >= 16 && gy0 <= 488) {
      // interior: all 32 halo rows in-bounds -> straight-line 32 float4 loads
      const float* hp0 = hb + plane + (size_t)(gy0 - HALF) * NW + gx0;
      #pragma unroll
      for (int m = 0; m < 32; ++m) {
        float4 v = *reinterpret_cast<const float4*>(hp0 + (size_t)m * NW);
        #pragma unroll
        for (int k = 0; k < 8; ++k) {
          int wi = m - k;                     // compile-time after unroll
          if (wi >= 0 && wi <= 24) {
            float wt = w[wi];
            a[k][0] = fmaf(wt, v.x, a[k][0]);
            a[k][1] = fmaf(wt, v.y, a[k][1]);
            a[k][2] = fmaf(wt, v.z, a[k][2]);
            a[k][3] = fmaf(wt, v.w, a[k][3]);
          }
        }
      }
    } else {
      // y-edge sub-strips (4 of 64): guarded per-row
      const float* hp = hb + plane + gx0;
      #pragma unroll
      for (int m = 0; m < 32; ++m) {
        int gy = gy0 - HALF + m;
        if ((unsigned)gy < (unsigned)NH) {
          float4 v = *reinterpret_cast<const float4*>(hp + (size_t)gy * NW);
          #pragma unroll
          for (int k = 0; k < 8; ++k) {
            int wi = m - k;
            if (wi >= 0 && wi <= 24) {
              float wt = w[wi];
              a[k][0] = fmaf(wt, v.x, a[k][0]);
              a[k][1] = fmaf(wt, v.y, a[k][1]);
              a[k][2] = fmaf(wt, v.z, a[k][2]);
              a[k][3] = fmaf(wt, v.w, a[k][3]);
            }
          }
        }
      }
    }
    #pragma unroll
    for (int k = 0; k < 8; ++k) {
      a[k][0] = clip01(a[k][0]); a[k][1] = clip01(a[k][1]);
      a[k][2] = clip01(a[k][2]); a[k][3] = clip01(a[k][3]);
    }
  } else {
    const float* xp = x + plane + gx0;
    #pragma unroll
    for (int k = 0; k < 8; ++k) {
      float4 v = *reinterpret_cast<const float4*>(xp + (size_t)(gy0 + k) * NW);
      a[k][0] = v.x; a[k][1] = v.y; a[k][2] = v.z; a[k][3] = v.w;
    }
  }
  chain_quad(a, P, b, gx0, gy0, noise_u + plane, nlist, packed, out + plane);
}

// ---- fallback (ws too small): r3's fused single kernel, no lists ----
__global__ __launch_bounds__(256, 4)
void fallback_kernel(const float* __restrict__ x, const float* __restrict__ sigma_u,
                     const float* __restrict__ glare_u, const float* __restrict__ occ_u,
                     const float* __restrict__ rain_u, const float* __restrict__ rain_n_u,
                     const float* __restrict__ rain_alpha_u, const float* __restrict__ noise_u,
                     const float* __restrict__ noise_amt_u, const int* __restrict__ flags,
                     float* __restrict__ out)
{
  const int b = blockIdx.z, ch = blockIdx.y;
  const int ty0 = (blockIdx.x >> 3) * 64, tx0 = (blockIdx.x & 7) * 64;
  const int tid = threadIdx.x;
  const int f0 = flags[b * 5] > 0;
  PParams P = load_params(b, flags, glare_u, occ_u, rain_alpha_u, noise_amt_u);
  const float nrain = floorf(20.f + 41.f * rain_n_u[b]);
  const size_t plane = (size_t)(b * NC + ch) * PLN;
  const float* xp = x + plane;
  const float* np = noise_u + plane;
  float* op = out + plane;

  __shared__ __align__(16) float s_hb[88 * 64];

  float wr[KS];
  if (f0) {
    float sig = 1.f + 3.f * sigma_u[b];
    float ninv = -1.f / (2.f * sig * sig);
    float s = 0.f;
    #pragma unroll
    for (int t = 0; t < KS; ++t) {
      float d = (float)t - 12.f;
      wr[t] = __expf(d * d * ninv); s += wr[t];
    }
    float inv = 1.f / s;
    #pragma unroll
    for (int t = 0; t < KS; ++t) wr[t] *= inv;

    for (int i = tid; i < 88 * 16; i += 256) {
      int r = i >> 4, q = i & 15;
      int gy = ty0 + r - HALF;
      float a0 = 0.f, a1 = 0.f, a2 = 0.f, a3 = 0.f;
      if ((unsigned)gy < (unsigned)NH) {
        const float* rowp = xp + (size_t)gy * NW;
        int gx0 = tx0 + q * 4;
        float win[28];
        if (gx0 - HALF >= 0 && gx0 + 15 < NW) {
          #pragma unroll
          for (int j = 0; j < 7; ++j) {
            float4 v = *reinterpret_cast<const float4*>(rowp + gx0 - HALF + 4 * j);
            win[4 * j + 0] = v.x; win[4 * j + 1] = v.y;
            win[4 * j + 2] = v.z; win[4 * j + 3] = v.w;
          }
        } else {
          #pragma unroll
          for (int j = 0; j < 28; ++j) {
            int gx = gx0 - HALF + j;
            win[j] = ((unsigned)gx < (unsigned)NW) ? rowp[gx] : 0.f;
          }
        }
        #pragma unroll
        for (int t = 0; t < KS; ++t) {
          float wt = wr[t];
          a0 = fmaf(wt, win[t + 0], a0);
          a1 = fmaf(wt, win[t + 1], a1);
          a2 = fmaf(wt, win[t + 2], a2);
          a3 = fmaf(wt, win[t + 3], a3);
        }
      }
      *reinterpret_cast<float4*>(&s_hb[r * 64 + (i & 15) * 4]) =
          make_float4(a0, a1, a2, a3);
    }
    __syncthreads();
  }

  for (int i = tid; i < 512; i += 256) {
    int xq = i & 63, sy = i >> 6;
    int gx = tx0 + xq, gy0 = ty0 + sy * 8;
    float acc[8];
    if (f0) {
      float wincol[32];
      #pragma unroll
      for (int j = 0; j < 32; ++j) wincol[j] = s_hb[(sy * 8 + j) * 64 + xq];
      #pragma unroll
      for (int k = 0; k < 8; ++k) {
        float a = 0.f;
        #pragma unroll
        for (int t = 0; t < KS; ++t) a = fmaf(wr[t], wincol[k + t], a);
        acc[k] = clip01(a);
      }
    } else {
      #pragma unroll
      for (int k = 0; k < 8; ++k) acc[k] = xp[(size_t)(gy0 + k) * NW + gx];
    }
    const float fx = (float)gx;
    if (P.f1) {
      float dx = (fx - P.cx) * P.rxi;
      float dx2 = dx * dx;
      #pragma unroll
      for (int k = 0; k < 8; ++k) {
        float dy = ((float)(gy0 + k) - P.cy) * P.ryi;
        acc[k] = clip01(acc[k] + P.intensity * __expf(-(dx2 + dy * dy)));
      }
    }
    if (P.f2 && fx >= P.ox0 && fx < P.ox1) {
      #pragma unroll
      for (int k = 0; k < 8; ++k) {
        float fy = (float)(gy0 + k);
        if (fy >= P.oy0 && fy < P.oy1) acc[k] = 0.f;
      }
    }
    if (P.f3) {
      float cnt[8];
      #pragma unroll
      for (int k = 0; k < 8; ++k) cnt[k] = 0.f;
      for (int s = 0; s < NS; ++s) {
        if ((float)s < nrain) {
          float xc = floorf(rain_u[(b * NS + s) * 3 + 0] * 512.f);
          if (fx >= xc - 1.f && fx <= xc) {
            float y0 = floorf(rain_u[(b * NS + s) * 3 + 1] * 256.f);
            float y1 = 256.f + floorf(rain_u[(b * NS + s) * 3 + 2] * 256.f);
            #pragma unroll
            for (int k = 0; k < 8; ++k) {
              float fy = (float)(gy0 + k);
              cnt[k] += (fy >= y0 && fy < y1) ? 1.f : 0.f;
            }
          }
        }
      }
      #pragma unroll
      for (int k = 0; k < 8; ++k) {
        if (cnt[k] != 0.f) {
          float d = exp2f(cnt[k] * P.log1ma);
          acc[k] = clip01(acc[k] * d + (1.f - d));
        }
      }
    }
    if (P.f4) {
      #pragma unroll
      for (int k = 0; k < 8; ++k) {
        float nv = np[(size_t)(gy0 + k) * NW + gx];
        acc[k] = (nv < P.thr_lo) ? 0.f : ((nv > P.thr_hi) ? 1.f : acc[k]);
      }
    }
    #pragma unroll
    for (int k = 0; k < 8; ++k) op[(size_t)(gy0 + k) * NW + gx] = acc[k];
  }
}

extern "C" void kernel_launch(void* const* d_in, const int* in_sizes, int n_in,
                              void* d_out, int out_size, void* d_ws, size_t ws_size,
                              hipStream_t stream)
{
  const float* x            = (const float*)d_in[0];
  const float* sigma_u      = (const float*)d_in[1];
  const float* glare_u      = (const float*)d_in[2];
  const float* occ_u        = (const float*)d_in[3];
  const float* rain_u       = (const float*)d_in[4];
  const float* rain_n_u     = (const float*)d_in[5];
  const float* rain_alpha_u = (const float*)d_in[6];
  const float* noise_u      = (const float*)d_in[7];
  const float* noise_amt_u  = (const float*)d_in[8];
  const int*   flags        = (const int*)d_in[9];
  float* out = (float*)d_out;

  if (ws_size >= WS_NEED) {
    float*    hb     = (float*)d_ws;
    float*    wts    = (float*)((char*)d_ws + WTS_OFF);
    int*      nlist  = (int*)((char*)d_ws + NL_OFF);
    unsigned* packed = (unsigned*)((char*)d_ws + PK_OFF);

    prep_kernel<<<65, 256, 0, stream>>>(rain_u, rain_n_u, sigma_u, nlist, packed, wts);
    hblur_kernel<<<dim3(NH / 2, NC, NB), 256, 0, stream>>>(x, flags, wts, hb);
    vchain_kernel<<<3072, 256, 0, stream>>>(
        x, hb, wts, glare_u, occ_u, rain_alpha_u, noise_u, noise_amt_u,
        flags, nlist, packed, out);
  } else {
    dim3 grid(64, NC, NB);
    fallback_kernel<<<grid, 256, 0, stream>>>(
        x, sigma_u, glare_u, occ_u, rain_u, rain_n_u, rain_alpha_u,
        noise_u, noise_amt_u, flags, out);
  }
}